// Round 8
// baseline (153.281 us; speedup 1.0000x reference)
//
#include <hip/hip_runtime.h>

#define NPOS 32768   // 32 * 32 * 32 positions
#define DDIM 256
#define KCODES 1024

typedef __attribute__((ext_vector_type(8))) short bf16x8;
typedef __attribute__((ext_vector_type(4))) float f32x4;
typedef unsigned long long u64;

// ---- fp32 ops with anti-contraction barriers (replicate numpy rounding) ----
__device__ __forceinline__ float sqr_rn(float x) {
    float r = x * x;
    asm volatile("" : "+v"(r));
    return r;
}
__device__ __forceinline__ float add_rn(float a, float b) {
    float r = a + b;
    asm volatile("" : "+v"(r));
    return r;
}

// fp32 -> bf16 round-to-nearest-even
__device__ __forceinline__ unsigned short f2bf(float x) {
    unsigned u = __float_as_uint(x);
    return (unsigned short)((u + 0x7fffu + ((u >> 16) & 1u)) >> 16);
}

// monotone pack: float score -> order-preserving u32, | code in low bits
__device__ __forceinline__ u64 packm(float s, int code) {
    unsigned b = __float_as_uint(s);
    unsigned mm = ((unsigned)((int)b >> 31)) | 0x80000000u;
    return ((u64)(b ^ mm) << 32) | (unsigned)code;
}

// ---------------- prep: fused zconv + wprep (one launch) ----------------
// blocks [0,1024): zconv — fp32 NCHW -> bf16 tiled [mtile][kk][kq][m].
// blocks [1024,1088): wprep — numpy-exact wsq + bf16 tiled [ntile][kk][kq][n].
__global__ __launch_bounds__(256) void prep(const float* __restrict__ z,
                                            const float* __restrict__ W,
                                            float* __restrict__ wsq,
                                            unsigned short* __restrict__ zb16t,
                                            unsigned short* __restrict__ wb16t) {
    __shared__ unsigned short Ls[8 * 1024];   // 16 KB (zconv only)
    const int t = threadIdx.x;
    if (blockIdx.x < 1024) {
        const int img = blockIdx.x >> 5;
        const int dc  = blockIdx.x & 31;      // d-chunk: d = dc*8 + e
        const int kk  = dc >> 2, kq = dc & 3;
        const float* zr = z + img * (DDIM * 1024) + dc * 8 * 1024;
#pragma unroll
        for (int e = 0; e < 8; ++e) {
            const float4 v = *(const float4*)&zr[e * 1024 + t * 4];
            unsigned short* o = &Ls[e * 1024 + t * 4];
            o[0] = f2bf(v.x); o[1] = f2bf(v.y); o[2] = f2bf(v.z); o[3] = f2bf(v.w);
        }
        __syncthreads();
#pragma unroll
        for (int j = 0; j < 4; ++j) {
            const int m = t + j * 256;        // position within image
            const int mtile = img * 8 + (m >> 7);
            bf16x8 o;
#pragma unroll
            for (int e = 0; e < 8; ++e) o[e] = (short)Ls[e * 1024 + m];
            *(bf16x8*)&zb16t[mtile * 32768 + kk * 4096 + kq * 1024 + (m & 127) * 8] = o;
        }
    } else {
        const int bid = blockIdx.x - 1024;
        const int row = bid * 16 + (t >> 4);
        const int j   = t & 15;
        const float* base = W + row * DDIM + (j & 7) + (j >> 3) * 128;
        float r = sqr_rn(base[0]);
#pragma unroll
        for (int i = 1; i < 16; ++i) r = add_rn(r, sqr_rn(base[i * 8]));
#pragma unroll
        for (int m = 1; m <= 8; m <<= 1) r = add_rn(r, __shfl_xor(r, m));
        if (j == 0) wsq[row] = r;
#pragma unroll
        for (int jj = 0; jj < 2; ++jj) {
            const int u  = t + jj * 256;      // 512 units = 16 rows x 32 k8
            const int n  = bid * 16 + (u >> 5);
            const int k8 = u & 31;
            const float4 f0 = *(const float4*)&W[n * DDIM + k8 * 8];
            const float4 f1 = *(const float4*)&W[n * DDIM + k8 * 8 + 4];
            bf16x8 o;
            o[0] = (short)f2bf(f0.x); o[1] = (short)f2bf(f0.y);
            o[2] = (short)f2bf(f0.z); o[3] = (short)f2bf(f0.w);
            o[4] = (short)f2bf(f1.x); o[5] = (short)f2bf(f1.y);
            o[6] = (short)f2bf(f1.z); o[7] = (short)f2bf(f1.w);
            const int kk = k8 >> 2, kq = k8 & 3;
            *(bf16x8*)&wb16t[(n >> 8) * 65536 + kk * 8192 + kq * 2048 + (n & 255) * 8] = o;
        }
    }
}

// ---------------- bf16 MFMA GEMM + per-block top-2 filter ----------------
// Grid 1024: mblk = bid>>2 (128 pos), nblk = bid&3 (256 codes). 4 waves.
// Tiled global layout IS fragment order: fragments load straight to VGPRs
// with plain dwordx4 — no LDS staging, NO barriers in the K-loop, so loads
// pipeline freely across iterations (12 independent loads in flight/wave).
__global__ __launch_bounds__(256) __attribute__((amdgpu_waves_per_eu(2, 2)))
void gemm_top2(const unsigned short* __restrict__ zb16t,
               const unsigned short* __restrict__ wb16t,
               const float* __restrict__ wsq, u64* __restrict__ cand) {
    __shared__ u64 redU[4096];              // 32 KB, epilogue reduction only

    const int t    = threadIdx.x;
    const int w    = t >> 6;
    const int l    = t & 63;
    const int ln   = l & 15;
    const int q    = l >> 4;
    const int mw   = (w & 1) * 64;
    const int nw   = (w >> 1) * 128;
    const int mblk = blockIdx.x >> 2;
    const int nblk = blockIdx.x & 3;
    const int m0   = mblk * 128;
    const int n0   = nblk * 256;

    // per-lane fragment base addresses (A[m=ln][k=q*8+j], B[n=ln][k=q*8+j])
    const char* aLane = (const char*)zb16t + (size_t)mblk * 65536 + q * 2048 + (mw + ln) * 16;
    const char* bLane = (const char*)wb16t + (size_t)nblk * 131072 + q * 4096 + (nw + ln) * 16;

    f32x4 acc[4][8];
#pragma unroll
    for (int a = 0; a < 4; ++a)
#pragma unroll
        for (int b = 0; b < 8; ++b) acc[a][b] = (f32x4)(0.f);

#pragma unroll 1
    for (int kk = 0; kk < 8; ++kk) {
        bf16x8 afr[4], bfr[8];
#pragma unroll
        for (int mf = 0; mf < 4; ++mf)
            afr[mf] = *(const bf16x8*)(aLane + kk * 8192 + mf * 256);
#pragma unroll
        for (int nf = 0; nf < 8; ++nf)
            bfr[nf] = *(const bf16x8*)(bLane + kk * 16384 + nf * 256);
#pragma unroll
        for (int nf = 0; nf < 8; ++nf)
#pragma unroll
            for (int mf = 0; mf < 4; ++mf)
                acc[mf][nf] = __builtin_amdgcn_mfma_f32_16x16x32_bf16(
                    afr[mf], bfr[nf], acc[mf][nf], 0, 0, 0);
    }

    // ---- epilogue: approx score = wsq - 2*acc, per-row top-2 (verified r4-r7) ----
    float wq[8];
#pragma unroll
    for (int nf = 0; nf < 8; ++nf) wq[nf] = wsq[n0 + nw + nf * 16 + ln];

#pragma unroll
    for (int mf = 0; mf < 4; ++mf) {
#pragma unroll
        for (int reg = 0; reg < 4; ++reg) {
            const int row = mw + mf * 16 + q * 4 + reg;
            float s0 = 1e30f, s1 = 1e30f;
            int   i0 = 0,     i1 = 0;
#pragma unroll
            for (int nf = 0; nf < 8; ++nf) {
                const float s  = fmaf(-2.f, acc[mf][nf][reg], wq[nf]);
                const int   cc = n0 + nw + nf * 16 + ln;
                if (s < s0)      { s1 = s0; i1 = i0; s0 = s; i0 = cc; }
                else if (s < s1) { s1 = s; i1 = cc; }
            }
            u64 p0 = packm(s0, i0), p1 = packm(s1, i1);
            const u64 o0 = __shfl_xor(p0, 1);
            const u64 o1 = __shfl_xor(p1, 1);
            const u64 c0 = (p0 < o0) ? p0 : o0;
            const u64 hi = (p0 < o0) ? o0 : p0;
            const u64 lo = (p1 < o1) ? p1 : o1;
            const u64 c1 = (hi < lo) ? hi : lo;
            if ((ln & 1) == 0) {
                u64* slot = &redU[row * 32 + (w >> 1) * 16 + (ln >> 1) * 2];
                slot[0] = c0;
                slot[1] = c1;
            }
        }
    }
    __syncthreads();
    {
        const int r2 = t >> 1, half = t & 1;
        u64 c0 = ~0ull, c1 = ~0ull;
#pragma unroll
        for (int j = 0; j < 16; ++j) {
            const u64 v = redU[r2 * 32 + half * 16 + j];
            if (v < c0)      { c1 = c0; c0 = v; }
            else if (v < c1) { c1 = v; }
        }
        __syncthreads();
        redU[r2 * 4 + half * 2]     = c0;
        redU[r2 * 4 + half * 2 + 1] = c1;
    }
    __syncthreads();
    if (t < 128) {
        const u64 a = redU[t * 4], b = redU[t * 4 + 1];
        const u64 c = redU[t * 4 + 2], d = redU[t * 4 + 3];
        const u64 m1 = (a < c) ? a : c;
        const u64 hi = (a < c) ? c : a;
        const u64 lo = (b < d) ? b : d;
        const u64 m2 = (hi < lo) ? hi : lo;
        u64* o = &cand[(u64)(m0 + t) * 8 + nblk * 2];
        o[0] = m1;
        o[1] = m2;
    }
}

// ---------------- exact numpy-bit rescore + in-kernel numpy-exact zsq ----------------
#define ZS 260   // floats per LDS row (bank-spread)
__global__ __launch_bounds__(256) void rescore(const float* __restrict__ z,
                                               const float* __restrict__ W,
                                               const float* __restrict__ wsq,
                                               const u64* __restrict__ cand,
                                               int* __restrict__ out) {
    __shared__ float Zs[32 * ZS];   // 33.3 KB, [p][d] fp32
    const int t  = threadIdx.x;
    const int m0 = blockIdx.x * 32;
    const float* zimg = z + (m0 >> 10) * (DDIM * 1024) + (m0 & 1023);
#pragma unroll
    for (int j = 0; j < 8; ++j) {
        const int f4 = t + j * 256;
        const int d = f4 >> 3, p4 = f4 & 7;
        const float4 v = *(const float4*)&zimg[d * 1024 + p4 * 4];
        Zs[(p4 * 4 + 0) * ZS + d] = v.x;
        Zs[(p4 * 4 + 1) * ZS + d] = v.y;
        Zs[(p4 * 4 + 2) * ZS + d] = v.z;
        Zs[(p4 * 4 + 3) * ZS + d] = v.w;
    }
    __syncthreads();
    const int pl = t >> 3, slot = t & 7;
    const int p = m0 + pl;
    const float* zr = &Zs[pl * ZS];

    // numpy-exact zsq: slot s owns chain s of each 128-half (sequential 16);
    // xor1/xor2/xor4 butterfly = ((r0+r1)+(r2+r3))+((r4+r5)+(r6+r7)) per half
    // (IEEE add commutative -> bit-identical); halves joined last.
    float h0 = sqr_rn(zr[slot]);
    float h1 = sqr_rn(zr[128 + slot]);
#pragma unroll
    for (int i = 1; i < 16; ++i) {
        h0 = add_rn(h0, sqr_rn(zr[slot + 8 * i]));
        h1 = add_rn(h1, sqr_rn(zr[128 + slot + 8 * i]));
    }
#pragma unroll
    for (int m = 1; m <= 4; m <<= 1) {
        h0 = add_rn(h0, __shfl_xor(h0, m));
        h1 = add_rn(h1, __shfl_xor(h1, m));
    }
    const float zq = add_rn(h0, h1);

    const int code = (int)(unsigned)(cand[(u64)p * 8 + slot] & 0xffffffffULL);
    const float* wr = W + code * DDIM;
    // sequential fma chain over d ascending — bit-identical to verified path
    float M = 0.f;
#pragma unroll 8
    for (int d4 = 0; d4 < 64; ++d4) {
        const float4 zv = *(const float4*)&zr[d4 * 4];
        const float4 wv = *(const float4*)&wr[d4 * 4];
        M = fmaf(zv.x, wv.x, M);
        M = fmaf(zv.y, wv.y, M);
        M = fmaf(zv.z, wv.z, M);
        M = fmaf(zv.w, wv.w, M);
    }
    const float s = add_rn(fmaf(-2.f, M, zq), wsq[code]);
    u64 v = ((u64)__float_as_uint(s) << 32) | (unsigned)code;
#pragma unroll
    for (int m = 1; m <= 4; m <<= 1) {
        const u64 o = __shfl_xor(v, m);
        if (o < v) v = o;
    }
    if (slot == 0) out[p] = (int)(unsigned)(v & 0xffffffffULL);
}

extern "C" void kernel_launch(void* const* d_in, const int* in_sizes, int n_in,
                              void* d_out, int out_size, void* d_ws, size_t ws_size,
                              hipStream_t stream) {
    const float* z = (const float*)d_in[0];   // [32, 256, 32, 32] NCHW
    const float* W = (const float*)d_in[1];   // [1024, 256]
    int* out = (int*)d_out;                   // [32768] int32 indices

    char* ws = (char*)d_ws;
    float*          wsq   = (float*)ws;                        //   4 KB @ 0
    u64*            cand  = (u64*)(ws + 4096);                 //   2 MB
    unsigned short* zb16t = (unsigned short*)(ws + 2101248);   //  16 MB
    unsigned short* wb16t = (unsigned short*)(ws + 18878464);  // 512 KB

    prep<<<1024 + KCODES / 16, 256, 0, stream>>>(z, W, wsq, zb16t, wb16t);
    gemm_top2<<<(NPOS / 128) * 4, 256, 0, stream>>>(zb16t, wb16t, wsq, cand);
    rescore<<<NPOS / 32, 256, 0, stream>>>(z, W, wsq, cand, out);
}

// Round 9
// 146.372 us; speedup vs baseline: 1.0472x; 1.0472x over previous
//
#include <hip/hip_runtime.h>

#define NPOS 32768   // 32 * 32 * 32 positions
#define DDIM 256
#define KCODES 1024

typedef __attribute__((ext_vector_type(8))) short bf16x8;
typedef __attribute__((ext_vector_type(4))) float f32x4;
typedef unsigned long long u64;

// ---- fp32 ops with anti-contraction barriers (replicate numpy rounding) ----
__device__ __forceinline__ float sqr_rn(float x) {
    float r = x * x;
    asm volatile("" : "+v"(r));
    return r;
}
__device__ __forceinline__ float add_rn(float a, float b) {
    float r = a + b;
    asm volatile("" : "+v"(r));
    return r;
}

// fp32 -> bf16 round-to-nearest-even
__device__ __forceinline__ unsigned short f2bf(float x) {
    unsigned u = __float_as_uint(x);
    return (unsigned short)((u + 0x7fffu + ((u >> 16) & 1u)) >> 16);
}

// monotone pack: float score -> order-preserving u32, | code in low bits
__device__ __forceinline__ u64 packm(float s, int code) {
    unsigned b = __float_as_uint(s);
    unsigned mm = ((unsigned)((int)b >> 31)) | 0x80000000u;
    return ((u64)(b ^ mm) << 32) | (unsigned)code;
}

// ---------------- prep: fused zconv + wprep (one launch) ----------------
__global__ __launch_bounds__(256) void prep(const float* __restrict__ z,
                                            const float* __restrict__ W,
                                            float* __restrict__ wsq,
                                            unsigned short* __restrict__ zb16t,
                                            unsigned short* __restrict__ wb16t) {
    __shared__ unsigned short Ls[8 * 1024];   // 16 KB (zconv only)
    const int t = threadIdx.x;
    if (blockIdx.x < 1024) {
        const int img = blockIdx.x >> 5;
        const int dc  = blockIdx.x & 31;      // d-chunk: d = dc*8 + e
        const int kk  = dc >> 2, kq = dc & 3;
        const float* zr = z + img * (DDIM * 1024) + dc * 8 * 1024;
#pragma unroll
        for (int e = 0; e < 8; ++e) {
            const float4 v = *(const float4*)&zr[e * 1024 + t * 4];
            unsigned short* o = &Ls[e * 1024 + t * 4];
            o[0] = f2bf(v.x); o[1] = f2bf(v.y); o[2] = f2bf(v.z); o[3] = f2bf(v.w);
        }
        __syncthreads();
#pragma unroll
        for (int j = 0; j < 4; ++j) {
            const int m = t + j * 256;        // position within image
            const int mtile = img * 8 + (m >> 7);
            bf16x8 o;
#pragma unroll
            for (int e = 0; e < 8; ++e) o[e] = (short)Ls[e * 1024 + m];
            *(bf16x8*)&zb16t[mtile * 32768 + kk * 4096 + kq * 1024 + (m & 127) * 8] = o;
        }
    } else {
        const int bid = blockIdx.x - 1024;
        const int row = bid * 16 + (t >> 4);
        const int j   = t & 15;
        const float* base = W + row * DDIM + (j & 7) + (j >> 3) * 128;
        float r = sqr_rn(base[0]);
#pragma unroll
        for (int i = 1; i < 16; ++i) r = add_rn(r, sqr_rn(base[i * 8]));
#pragma unroll
        for (int m = 1; m <= 8; m <<= 1) r = add_rn(r, __shfl_xor(r, m));
        if (j == 0) wsq[row] = r;
#pragma unroll
        for (int jj = 0; jj < 2; ++jj) {
            const int u  = t + jj * 256;      // 512 units = 16 rows x 32 k8
            const int n  = bid * 16 + (u >> 5);
            const int k8 = u & 31;
            const float4 f0 = *(const float4*)&W[n * DDIM + k8 * 8];
            const float4 f1 = *(const float4*)&W[n * DDIM + k8 * 8 + 4];
            bf16x8 o;
            o[0] = (short)f2bf(f0.x); o[1] = (short)f2bf(f0.y);
            o[2] = (short)f2bf(f0.z); o[3] = (short)f2bf(f0.w);
            o[4] = (short)f2bf(f1.x); o[5] = (short)f2bf(f1.y);
            o[6] = (short)f2bf(f1.z); o[7] = (short)f2bf(f1.w);
            const int kk = k8 >> 2, kq = k8 & 3;
            *(bf16x8*)&wb16t[(n >> 8) * 65536 + kk * 8192 + kq * 2048 + (n & 255) * 8] = o;
        }
    }
}

// ---------------- bf16 MFMA GEMM + per-block top-2 filter ----------------
// Grid 1024: mblk = bid>>2 (128 pos), nblk = bid&3 (256 codes). 4 waves.
// Fragments load straight from tiled global to VGPRs (no LDS, no K-loop
// barrier). Software pipeline: A-frags (HBM/L3-latency stream) are
// register-double-buffered one kk ahead; B-frags (L2-hot) load on demand.
__global__ __launch_bounds__(256) __attribute__((amdgpu_waves_per_eu(2, 2)))
void gemm_top2(const unsigned short* __restrict__ zb16t,
               const unsigned short* __restrict__ wb16t,
               const float* __restrict__ wsq, u64* __restrict__ cand) {
    __shared__ u64 redU[4096];              // 32 KB, epilogue reduction only

    const int t    = threadIdx.x;
    const int w    = t >> 6;
    const int l    = t & 63;
    const int ln   = l & 15;
    const int q    = l >> 4;
    const int mw   = (w & 1) * 64;
    const int nw   = (w >> 1) * 128;
    const int mblk = blockIdx.x >> 2;
    const int nblk = blockIdx.x & 3;
    const int m0   = mblk * 128;
    const int n0   = nblk * 256;

    // per-lane fragment base addresses (A[m=ln][k=q*8+j], B[n=ln][k=q*8+j])
    const char* aLane = (const char*)zb16t + (size_t)mblk * 65536 + q * 2048 + (mw + ln) * 16;
    const char* bLane = (const char*)wb16t + (size_t)nblk * 131072 + q * 4096 + (nw + ln) * 16;

    f32x4 acc[4][8];
#pragma unroll
    for (int a = 0; a < 4; ++a)
#pragma unroll
        for (int b = 0; b < 8; ++b) acc[a][b] = (f32x4)(0.f);

    // prologue: A-frags for kk=0
    bf16x8 afr[4], anx[4];
#pragma unroll
    for (int mf = 0; mf < 4; ++mf)
        afr[mf] = *(const bf16x8*)(aLane + mf * 256);

#pragma unroll 1
    for (int kk = 0; kk < 8; ++kk) {
        // B for this kk first (shortest slack), then A for kk+1 (full-iter slack)
        bf16x8 bfr[8];
#pragma unroll
        for (int nf = 0; nf < 8; ++nf)
            bfr[nf] = *(const bf16x8*)(bLane + kk * 16384 + nf * 256);
        if (kk < 7) {
#pragma unroll
            for (int mf = 0; mf < 4; ++mf)
                anx[mf] = *(const bf16x8*)(aLane + (kk + 1) * 8192 + mf * 256);
        }
#pragma unroll
        for (int nf = 0; nf < 8; ++nf)
#pragma unroll
            for (int mf = 0; mf < 4; ++mf)
                acc[mf][nf] = __builtin_amdgcn_mfma_f32_16x16x32_bf16(
                    afr[mf], bfr[nf], acc[mf][nf], 0, 0, 0);
#pragma unroll
        for (int mf = 0; mf < 4; ++mf) afr[mf] = anx[mf];
    }

    // ---- epilogue: approx score = wsq - 2*acc, per-row top-2 (verified r4-r8) ----
    float wq[8];
#pragma unroll
    for (int nf = 0; nf < 8; ++nf) wq[nf] = wsq[n0 + nw + nf * 16 + ln];

#pragma unroll
    for (int mf = 0; mf < 4; ++mf) {
#pragma unroll
        for (int reg = 0; reg < 4; ++reg) {
            const int row = mw + mf * 16 + q * 4 + reg;
            float s0 = 1e30f, s1 = 1e30f;
            int   i0 = 0,     i1 = 0;
#pragma unroll
            for (int nf = 0; nf < 8; ++nf) {
                const float s  = fmaf(-2.f, acc[mf][nf][reg], wq[nf]);
                const int   cc = n0 + nw + nf * 16 + ln;
                if (s < s0)      { s1 = s0; i1 = i0; s0 = s; i0 = cc; }
                else if (s < s1) { s1 = s; i1 = cc; }
            }
            u64 p0 = packm(s0, i0), p1 = packm(s1, i1);
            const u64 o0 = __shfl_xor(p0, 1);
            const u64 o1 = __shfl_xor(p1, 1);
            const u64 c0 = (p0 < o0) ? p0 : o0;
            const u64 hi = (p0 < o0) ? o0 : p0;
            const u64 lo = (p1 < o1) ? p1 : o1;
            const u64 c1 = (hi < lo) ? hi : lo;
            if ((ln & 1) == 0) {
                u64* slot = &redU[row * 32 + (w >> 1) * 16 + (ln >> 1) * 2];
                slot[0] = c0;
                slot[1] = c1;
            }
        }
    }
    __syncthreads();
    {
        const int r2 = t >> 1, half = t & 1;
        u64 c0 = ~0ull, c1 = ~0ull;
#pragma unroll
        for (int j = 0; j < 16; ++j) {
            const u64 v = redU[r2 * 32 + half * 16 + j];
            if (v < c0)      { c1 = c0; c0 = v; }
            else if (v < c1) { c1 = v; }
        }
        __syncthreads();
        redU[r2 * 4 + half * 2]     = c0;
        redU[r2 * 4 + half * 2 + 1] = c1;
    }
    __syncthreads();
    if (t < 128) {
        const u64 a = redU[t * 4], b = redU[t * 4 + 1];
        const u64 c = redU[t * 4 + 2], d = redU[t * 4 + 3];
        const u64 m1 = (a < c) ? a : c;
        const u64 hi = (a < c) ? c : a;
        const u64 lo = (b < d) ? b : d;
        const u64 m2 = (hi < lo) ? hi : lo;
        u64* o = &cand[(u64)(m0 + t) * 8 + nblk * 2];
        o[0] = m1;
        o[1] = m2;
    }
}

// ---------------- exact numpy-bit rescore + in-kernel numpy-exact zsq ----------------
#define ZS 260   // floats per LDS row (bank-spread)
__global__ __launch_bounds__(256) void rescore(const float* __restrict__ z,
                                               const float* __restrict__ W,
                                               const float* __restrict__ wsq,
                                               const u64* __restrict__ cand,
                                               int* __restrict__ out) {
    __shared__ float Zs[32 * ZS];   // 33.3 KB, [p][d] fp32
    const int t  = threadIdx.x;
    const int m0 = blockIdx.x * 32;
    const float* zimg = z + (m0 >> 10) * (DDIM * 1024) + (m0 & 1023);
#pragma unroll
    for (int j = 0; j < 8; ++j) {
        const int f4 = t + j * 256;
        const int d = f4 >> 3, p4 = f4 & 7;
        const float4 v = *(const float4*)&zimg[d * 1024 + p4 * 4];
        Zs[(p4 * 4 + 0) * ZS + d] = v.x;
        Zs[(p4 * 4 + 1) * ZS + d] = v.y;
        Zs[(p4 * 4 + 2) * ZS + d] = v.z;
        Zs[(p4 * 4 + 3) * ZS + d] = v.w;
    }
    __syncthreads();
    const int pl = t >> 3, slot = t & 7;
    const int p = m0 + pl;
    const float* zr = &Zs[pl * ZS];

    // numpy-exact zsq: slot s owns chain s of each 128-half (sequential 16);
    // xor1/xor2/xor4 butterfly = ((r0+r1)+(r2+r3))+((r4+r5)+(r6+r7)) per half
    // (IEEE add commutative -> bit-identical); halves joined last.
    float h0 = sqr_rn(zr[slot]);
    float h1 = sqr_rn(zr[128 + slot]);
#pragma unroll
    for (int i = 1; i < 16; ++i) {
        h0 = add_rn(h0, sqr_rn(zr[slot + 8 * i]));
        h1 = add_rn(h1, sqr_rn(zr[128 + slot + 8 * i]));
    }
#pragma unroll
    for (int m = 1; m <= 4; m <<= 1) {
        h0 = add_rn(h0, __shfl_xor(h0, m));
        h1 = add_rn(h1, __shfl_xor(h1, m));
    }
    const float zq = add_rn(h0, h1);

    const int code = (int)(unsigned)(cand[(u64)p * 8 + slot] & 0xffffffffULL);
    const float* wr = W + code * DDIM;
    // sequential fma chain over d ascending — bit-identical to verified path
    float M = 0.f;
#pragma unroll 8
    for (int d4 = 0; d4 < 64; ++d4) {
        const float4 zv = *(const float4*)&zr[d4 * 4];
        const float4 wv = *(const float4*)&wr[d4 * 4];
        M = fmaf(zv.x, wv.x, M);
        M = fmaf(zv.y, wv.y, M);
        M = fmaf(zv.z, wv.z, M);
        M = fmaf(zv.w, wv.w, M);
    }
    const float s = add_rn(fmaf(-2.f, M, zq), wsq[code]);
    u64 v = ((u64)__float_as_uint(s) << 32) | (unsigned)code;
#pragma unroll
    for (int m = 1; m <= 4; m <<= 1) {
        const u64 o = __shfl_xor(v, m);
        if (o < v) v = o;
    }
    if (slot == 0) out[p] = (int)(unsigned)(v & 0xffffffffULL);
}

extern "C" void kernel_launch(void* const* d_in, const int* in_sizes, int n_in,
                              void* d_out, int out_size, void* d_ws, size_t ws_size,
                              hipStream_t stream) {
    const float* z = (const float*)d_in[0];   // [32, 256, 32, 32] NCHW
    const float* W = (const float*)d_in[1];   // [1024, 256]
    int* out = (int*)d_out;                   // [32768] int32 indices

    char* ws = (char*)d_ws;
    float*          wsq   = (float*)ws;                        //   4 KB @ 0
    u64*            cand  = (u64*)(ws + 4096);                 //   2 MB
    unsigned short* zb16t = (unsigned short*)(ws + 2101248);   //  16 MB
    unsigned short* wb16t = (unsigned short*)(ws + 18878464);  // 512 KB

    prep<<<1024 + KCODES / 16, 256, 0, stream>>>(z, W, wsq, zb16t, wb16t);
    gemm_top2<<<(NPOS / 128) * 4, 256, 0, stream>>>(zb16t, wb16t, wsq, cand);
    rescore<<<NPOS / 32, 256, 0, stream>>>(z, W, wsq, cand, out);
}